// Round 1
// baseline (269.102 us; speedup 1.0000x reference)
//
#include <hip/hip_runtime.h>
#include <math.h>

#define B_    32
#define H_    512
#define W_    512
#define NBINS 256
#define NT    254
#define RROWS 16      // output rows per block
#define CW    256     // output cols per block (== blockDim.x)

// ws layout:
//   [0      .. 32768)  int   hist[32][256]   (memset 0)
//   [32768  .. 32896)  float sq[32]          (memset 0)
//   [32896  .. 33024)  float t1[32]
//   [33024  .. 33152)  float t2[32]
//   [33152  .. 33280)  float sm[32]

// ---------------------------------------------------------------------------
// Kernel 1: 5x5 dilation (separable max) + per-batch histogram of images*255
// ---------------------------------------------------------------------------
__global__ __launch_bounds__(256) void k_hist(const float* __restrict__ labels,
                                              const float* __restrict__ images,
                                              int* __restrict__ hist) {
    __shared__ float s_lab[RROWS + 4][CW + 4];   // 20 x 260 halo tile
    __shared__ float s_hmax[RROWS + 4][CW];      // horizontal 5-max
    __shared__ int   s_hist[NBINS];

    const int tid   = threadIdx.x;
    const int chunk = blockIdx.x;   // 0..1
    const int rb    = blockIdx.y;   // 0..31
    const int b     = blockIdx.z;   // 0..31
    const int col0  = chunk * CW;
    const int row0  = rb * RROWS;
    const float* lab = labels + (size_t)b * H_ * W_;
    const float* img = images + (size_t)b * H_ * W_;

    s_hist[tid] = 0;

    // cooperative load of labels tile with 2-wide halo (zero padded)
    for (int idx = tid; idx < (RROWS + 4) * (CW + 4); idx += 256) {
        int r  = idx / (CW + 4);
        int c  = idx - r * (CW + 4);
        int gr = row0 - 2 + r;
        int gc = col0 - 2 + c;
        float v = 0.0f;
        if (gr >= 0 && gr < H_ && gc >= 0 && gc < W_) v = lab[gr * W_ + gc];
        s_lab[r][c] = v;
    }
    __syncthreads();

    // horizontal 5-tap max
    for (int idx = tid; idx < (RROWS + 4) * CW; idx += 256) {
        int r = idx >> 8;
        int c = idx & 255;
        float m = s_lab[r][c];
        m = fmaxf(m, s_lab[r][c + 1]);
        m = fmaxf(m, s_lab[r][c + 2]);
        m = fmaxf(m, s_lab[r][c + 3]);
        m = fmaxf(m, s_lab[r][c + 4]);
        s_hmax[r][c] = m;
    }
    __syncthreads();

    const float cscale = 256.0f / 255.0f;   // == f32(NBINS/255.0), bit-exact
    for (int rr = 0; rr < RROWS; ++rr) {
        float m = s_hmax[rr][tid];
        m = fmaxf(m, s_hmax[rr + 1][tid]);
        m = fmaxf(m, s_hmax[rr + 2][tid]);
        m = fmaxf(m, s_hmax[rr + 3][tid]);
        m = fmaxf(m, s_hmax[rr + 4][tid]);
        if (m > 0.0f) {
            float im = img[(row0 + rr) * W_ + col0 + tid];
            float v  = im * 255.0f;                 // matches reference v
            int bin  = (int)floorf(v * cscale);     // matches v*(NBINS/255.0)
            bin = bin < 0 ? 0 : (bin > NBINS - 1 ? NBINS - 1 : bin);
            atomicAdd(&s_hist[bin], 1);
        }
    }
    __syncthreads();

    int c = s_hist[tid];
    if (c) atomicAdd(&hist[b * NBINS + tid], c);
}

// ---------------------------------------------------------------------------
// Kernel 2: per-batch two-threshold Otsu argmax (one block per batch)
// ---------------------------------------------------------------------------
__global__ __launch_bounds__(256) void k_otsu(const int* __restrict__ hist,
                                              float* __restrict__ t1o,
                                              float* __restrict__ t2o,
                                              float* __restrict__ smo) {
    __shared__ float s_a[NBINS];    // ch (cumulative prob)
    __shared__ float s_b[NBINS];    // cm (cumulative mean)
    __shared__ float s_val[256];
    __shared__ int   s_idx[256];
    __shared__ float s_tot;

    const int tid = threadIdx.x;
    const int b   = blockIdx.x;

    s_a[tid] = (float)hist[b * NBINS + tid];
    __syncthreads();

    if (tid == 0) {
        float tot = 0.0f;
        for (int i = 0; i < NBINS; ++i) tot += s_a[i];   // exact: ints < 2^24
        s_tot = tot;
        float ch = 0.0f, cm = 0.0f;
        for (int i = 0; i < NBINS; ++i) {
            float p = s_a[i] / tot;
            ch += p;
            cm += p * (float)i;
            s_a[i] = ch;
            s_b[i] = cm;
        }
    }
    __syncthreads();

    const float tm = s_b[NBINS - 1];
    const float s  = 1e-8f;
    float bestv = -__builtin_inff();
    int   besti = 0x7fffffff;

    for (int k = tid; k < NT * NT; k += 256) {   // k increasing => first-max
        int i = k / NT;
        int j = k - i * NT;
        float w0 = s_a[i];
        float cb = s_a[j];
        float w1 = cb - w0;
        float w2 = 1.0f - cb;
        float m0 = s_b[i];
        float m1 = s_b[j];
        float mean0 = m0 / (w0 + s);
        float mean1 = (m1 - m0) / (w1 + s);
        float mean2 = (tm - m1) / (w2 + s);
        float d0 = mean0 - tm, d1 = mean1 - tm, d2 = mean2 - tm;
        float bv = w0 * d0 * d0 + w1 * d1 * d1 + w2 * d2 * d2;
        bool ok = (w0 > 0.0f) && (w1 > 0.0f) && (w2 > 0.0f);
        bv = ok ? bv : 0.0f;
        if (bv > bestv) { bestv = bv; besti = k; }
    }
    s_val[tid] = bestv;
    s_idx[tid] = besti;
    __syncthreads();
    for (int off = 128; off > 0; off >>= 1) {
        if (tid < off) {
            float ov = s_val[tid + off];
            int   oi = s_idx[tid + off];
            if (ov > s_val[tid] || (ov == s_val[tid] && oi < s_idx[tid])) {
                s_val[tid] = ov;
                s_idx[tid] = oi;
            }
        }
        __syncthreads();
    }
    if (tid == 0) {
        int am = s_idx[0];
        t1o[b] = (float)(am / NT + 1) / 255.0f;
        t2o[b] = (float)(am % NT + 1) / 255.0f;
        smo[b] = s_tot;
    }
}

// ---------------------------------------------------------------------------
// Kernel 3: recompute dilation, per-batch sum of (ci - pred)^2 on masked px
// ---------------------------------------------------------------------------
__global__ __launch_bounds__(256) void k_loss(const float* __restrict__ labels,
                                              const float* __restrict__ images,
                                              const float* __restrict__ preds,
                                              const float* __restrict__ t1a,
                                              const float* __restrict__ t2a,
                                              float* __restrict__ sq) {
    __shared__ float s_lab[RROWS + 4][CW + 4];
    __shared__ float s_hmax[RROWS + 4][CW];
    __shared__ float s_red[256];

    const int tid   = threadIdx.x;
    const int chunk = blockIdx.x;
    const int rb    = blockIdx.y;
    const int b     = blockIdx.z;
    const int col0  = chunk * CW;
    const int row0  = rb * RROWS;
    const float* lab = labels + (size_t)b * H_ * W_;
    const float* img = images + (size_t)b * H_ * W_;
    const float* prd = preds  + (size_t)b * H_ * W_;

    for (int idx = tid; idx < (RROWS + 4) * (CW + 4); idx += 256) {
        int r  = idx / (CW + 4);
        int c  = idx - r * (CW + 4);
        int gr = row0 - 2 + r;
        int gc = col0 - 2 + c;
        float v = 0.0f;
        if (gr >= 0 && gr < H_ && gc >= 0 && gc < W_) v = lab[gr * W_ + gc];
        s_lab[r][c] = v;
    }
    __syncthreads();
    for (int idx = tid; idx < (RROWS + 4) * CW; idx += 256) {
        int r = idx >> 8;
        int c = idx & 255;
        float m = s_lab[r][c];
        m = fmaxf(m, s_lab[r][c + 1]);
        m = fmaxf(m, s_lab[r][c + 2]);
        m = fmaxf(m, s_lab[r][c + 3]);
        m = fmaxf(m, s_lab[r][c + 4]);
        s_hmax[r][c] = m;
    }
    __syncthreads();

    const float t1 = t1a[b];
    const float t2 = t2a[b];
    float acc = 0.0f;
    for (int rr = 0; rr < RROWS; ++rr) {
        float m = s_hmax[rr][tid];
        m = fmaxf(m, s_hmax[rr + 1][tid]);
        m = fmaxf(m, s_hmax[rr + 2][tid]);
        m = fmaxf(m, s_hmax[rr + 3][tid]);
        m = fmaxf(m, s_hmax[rr + 4][tid]);
        if (m > 0.0f) {
            int off  = (row0 + rr) * W_ + col0 + tid;
            float im = img[off];
            float pr = prd[off];
            float ci = im >= t2 ? 1.0f : (im >= t1 ? 0.5f : 0.0f);
            float d  = ci - pr;
            acc += d * d;
        }
        // unmasked pixels: ci=0 (t1>=1/255>0), cpred=0 -> contribution 0
    }
    s_red[tid] = acc;
    __syncthreads();
    for (int off = 128; off > 0; off >>= 1) {
        if (tid < off) s_red[tid] += s_red[tid + off];
        __syncthreads();
    }
    if (tid == 0 && s_red[0] != 0.0f) atomicAdd(&sq[b], s_red[0]);
}

// ---------------------------------------------------------------------------
// Kernel 4: final valid-batch mean
// ---------------------------------------------------------------------------
__global__ __launch_bounds__(64) void k_final(const float* __restrict__ sq,
                                              const float* __restrict__ sm,
                                              float* __restrict__ out) {
    int t = threadIdx.x;
    float lp = 0.0f, vc = 0.0f;
    if (t < B_) {
        float smv  = sm[t] + 1e-8f;
        bool valid = smv > 1e-8f;
        if (valid) { lp = sq[t] / smv; vc = 1.0f; }
    }
    for (int off = 32; off > 0; off >>= 1) {
        lp += __shfl_down(lp, off);
        vc += __shfl_down(vc, off);
    }
    if (t == 0) {
        out[0] = vc > 0.0f ? lp / fmaxf(vc, 1.0f) : 0.0f;
    }
}

extern "C" void kernel_launch(void* const* d_in, const int* in_sizes, int n_in,
                              void* d_out, int out_size, void* d_ws, size_t ws_size,
                              hipStream_t stream) {
    const float* preds  = (const float*)d_in[0];
    const float* labels = (const float*)d_in[1];
    const float* images = (const float*)d_in[2];
    float* out = (float*)d_out;

    char* ws   = (char*)d_ws;
    int*   hist = (int*)ws;                       // 32*256*4 = 32768 B
    float* sq   = (float*)(ws + 32768);           // 128 B
    float* t1   = (float*)(ws + 32768 + 128);
    float* t2   = (float*)(ws + 32768 + 256);
    float* sm   = (float*)(ws + 32768 + 384);

    hipMemsetAsync(ws, 0, 32768 + 128, stream);   // hist + sq accumulators

    dim3 grid(W_ / CW, H_ / RROWS, B_);           // 2 x 32 x 32
    k_hist<<<grid, 256, 0, stream>>>(labels, images, hist);
    k_otsu<<<B_, 256, 0, stream>>>(hist, t1, t2, sm);
    k_loss<<<grid, 256, 0, stream>>>(labels, images, preds, t1, t2, sq);
    k_final<<<1, 64, 0, stream>>>(sq, sm, out);
}

// Round 2
// 168.459 us; speedup vs baseline: 1.5974x; 1.5974x over previous
//
#include <hip/hip_runtime.h>
#include <math.h>

#define B_    32
#define H_    512
#define W_    512
#define NBINS 256
#define NT    254

// ws layout:
//   [0      .. 32768)  int   hist[32][256]      (memset 0)
//   [32768  .. 33024)  ull   packed[32]         (memset 0)
//   [33024  .. 33152)  float sq[32]             (memset 0)
//   [33152  .. 33280)  float sm[32]
//   [33280  .. 33284)  int   counter            (memset 0)

__device__ __forceinline__ float max5(float a, float b, float c, float d, float e) {
    return fmaxf(fmaxf(fmaxf(a, b), fmaxf(c, d)), e);
}

__device__ __forceinline__ void hist_add(int* s_hist, float im) {
    float v = im * 255.0f;                       // matches reference v (rounded)
    float u = v * (256.0f / 255.0f);             // matches v*(NBINS/255.0) in f32
    int bin = (int)floorf(u);
    bin = bin < 0 ? 0 : (bin > NBINS - 1 ? NBINS - 1 : bin);
    atomicAdd(&s_hist[bin], 1);
}

// ---------------------------------------------------------------------------
// Kernel 1: 5x5 dilation (vertical max in registers, horizontal via LDS)
//           + per-batch histogram. Block = 256 thr, tile = 16 rows x 512 cols.
// ---------------------------------------------------------------------------
__global__ __launch_bounds__(256) void k_hist(const float* __restrict__ labels,
                                              const float* __restrict__ images,
                                              int* __restrict__ hist) {
    __shared__ float s_v[16][520];   // vmax, data at col+4, halo zeros at 0..3/516..519
    __shared__ int   s_hist[NBINS];

    const int tid   = threadIdx.x;
    const int band  = blockIdx.x;           // 0..31 (16-row bands)
    const int b     = blockIdx.y;           // batch
    const int strip = tid & 127;            // float4 column strip
    const int half  = tid >> 7;             // 0/1: rows 0..7 / 8..15 of tile
    const int c0    = strip * 4;
    const int rbase = band * 16 + half * 8;
    const float* lab = labels + (size_t)b * (H_ * W_);
    const float* img = images + (size_t)b * (H_ * W_);

    s_hist[tid] = 0;
    if (tid < 128) {                        // zero halo columns
        int r = tid >> 3, cc = tid & 7;
        s_v[r][cc < 4 ? cc : 512 + cc] = 0.0f;
    }

    // vertical 5-max: need label rows rbase-2 .. rbase+9 (12 rows)
    float4 l[12];
#pragma unroll
    for (int k = 0; k < 12; ++k) {
        int gr = rbase - 2 + k;
        if ((unsigned)gr < (unsigned)H_)
            l[k] = *(const float4*)(lab + (size_t)gr * W_ + c0);
        else
            l[k] = make_float4(0.f, 0.f, 0.f, 0.f);
    }
#pragma unroll
    for (int r = 0; r < 8; ++r) {
        float4 m;
        m.x = max5(l[r].x, l[r+1].x, l[r+2].x, l[r+3].x, l[r+4].x);
        m.y = max5(l[r].y, l[r+1].y, l[r+2].y, l[r+3].y, l[r+4].y);
        m.z = max5(l[r].z, l[r+1].z, l[r+2].z, l[r+3].z, l[r+4].z);
        m.w = max5(l[r].w, l[r+1].w, l[r+2].w, l[r+3].w, l[r+4].w);
        *(float4*)&s_v[half * 8 + r][c0 + 4] = m;
    }
    __syncthreads();

    // horizontal 5-max + conditional image read + histogram
#pragma unroll
    for (int r = 0; r < 8; ++r) {
        const float* f = &s_v[half * 8 + r][c0 + 2];
        float h0 = max5(f[0], f[1], f[2], f[3], f[4]);
        float h1 = max5(f[1], f[2], f[3], f[4], f[5]);
        float h2 = max5(f[2], f[3], f[4], f[5], f[6]);
        float h3 = max5(f[3], f[4], f[5], f[6], f[7]);
        if (h0 > 0.f || h1 > 0.f || h2 > 0.f || h3 > 0.f) {
            float4 iv = *(const float4*)(img + (size_t)(rbase + r) * W_ + c0);
            if (h0 > 0.f) hist_add(s_hist, iv.x);
            if (h1 > 0.f) hist_add(s_hist, iv.y);
            if (h2 > 0.f) hist_add(s_hist, iv.z);
            if (h3 > 0.f) hist_add(s_hist, iv.w);
        }
    }
    __syncthreads();
    int c = s_hist[tid];
    if (c) atomicAdd(&hist[b * NBINS + tid], c);
}

// ---------------------------------------------------------------------------
// Kernel 2: scan + two-threshold Otsu argmax. 8 i-slices x 32 batches.
// term0 depends only on i, term2 only on j -> 1 divide per pair.
// ---------------------------------------------------------------------------
__global__ __launch_bounds__(256) void k_search(const int* __restrict__ hist,
                                                unsigned long long* __restrict__ packed,
                                                float* __restrict__ sm) {
    __shared__ float sA[NBINS];      // ch
    __shared__ float sB[NBINS];      // cm
    __shared__ float sPQ[NBINS][2];  // p, p*i
    __shared__ float sT0[32];
    __shared__ float sT2[NBINS];
    __shared__ int   s_int[256];
    __shared__ unsigned long long s_pack[256];

    const int tid   = threadIdx.x;
    const int slice = blockIdx.x;    // 0..7
    const int b     = blockIdx.y;
    const float s   = 1e-8f;

    int h = hist[b * NBINS + tid];
    s_int[tid] = h;
    __syncthreads();
    for (int off = 128; off > 0; off >>= 1) {       // exact: integer counts
        if (tid < off) s_int[tid] += s_int[tid + off];
        __syncthreads();
    }
    const float ftot = (float)s_int[0];
    __syncthreads();

    float p = (float)h / ftot;
    sPQ[tid][0] = p;
    sPQ[tid][1] = p * (float)tid;
    __syncthreads();

    if (tid == 0) {                  // sequential fold: preserves reference rounding
        float ch = 0.0f, cm = 0.0f;
#pragma unroll 8
        for (int i = 0; i < NBINS; ++i) {
            ch += sPQ[i][0];
            cm += sPQ[i][1];
            sA[i] = ch;
            sB[i] = cm;
        }
    }
    __syncthreads();

    const float tm = sB[NBINS - 1];
    if (tid < NT) {                  // term2[j]
        float cb = sA[tid];
        float w2 = 1.0f - cb;
        float mean2 = (tm - sB[tid]) / (w2 + s);
        float d2 = mean2 - tm;
        sT2[tid] = w2 * (d2 * d2);
    }
    const int i0 = slice * 32;
    if (tid < 32) {                  // term0[i] for this slice
        int i = i0 + tid;
        if (i < NT) {
            float w0 = sA[i];
            float mean0 = sB[i] / (w0 + s);
            float d0 = mean0 - tm;
            sT0[tid] = w0 * (d0 * d0);
        }
    }
    __syncthreads();

    unsigned long long best = 0ull;
    if (tid < NT) {
        const float cb  = sA[tid];
        const float m1v = sB[tid];
        const float w2  = 1.0f - cb;
        const float t2v = sT2[tid];
#pragma unroll 4
        for (int il = 0; il < 32; ++il) {
            int i = i0 + il;
            if (i >= NT) break;
            float w0 = sA[i];
            float w1 = cb - w0;
            float mean1 = (m1v - sB[i]) / (w1 + s);
            float d1 = mean1 - tm;
            float bv = (sT0[il] + w1 * (d1 * d1)) + t2v;
            bool ok = (w0 > 0.f) && (w1 > 0.f) && (w2 > 0.f);
            bv = ok ? bv : 0.0f;
            unsigned k = (unsigned)(i * NT + tid);
            // bv >= 0 so float-bit order == value order; ~k gives first-max tie-break
            unsigned long long pk =
                ((unsigned long long)__float_as_uint(bv) << 32) | (0xFFFFFFFFu - k);
            best = pk > best ? pk : best;
        }
    }
    s_pack[tid] = best;
    __syncthreads();
    for (int off = 128; off > 0; off >>= 1) {
        if (tid < off) {
            unsigned long long o = s_pack[tid + off];
            if (o > s_pack[tid]) s_pack[tid] = o;
        }
        __syncthreads();
    }
    if (tid == 0) {
        atomicMax(&packed[b], s_pack[0]);
        if (slice == 0) sm[b] = ftot;
    }
}

// ---------------------------------------------------------------------------
// Kernel 3: recompute dilation, masked (ci-pred)^2, fused final reduction
// ---------------------------------------------------------------------------
__global__ __launch_bounds__(256) void k_loss(const float* __restrict__ labels,
                                              const float* __restrict__ images,
                                              const float* __restrict__ preds,
                                              const unsigned long long* __restrict__ packed,
                                              float* __restrict__ sq,
                                              const float* __restrict__ sm,
                                              int* __restrict__ counter,
                                              float* __restrict__ out) {
    __shared__ float s_v[16][520];
    __shared__ float s_red[256];
    __shared__ int   s_ticket;

    const int tid   = threadIdx.x;
    const int band  = blockIdx.x;
    const int b     = blockIdx.y;
    const int strip = tid & 127;
    const int half  = tid >> 7;
    const int c0    = strip * 4;
    const int rbase = band * 16 + half * 8;
    const float* lab = labels + (size_t)b * (H_ * W_);
    const float* img = images + (size_t)b * (H_ * W_);
    const float* prd = preds  + (size_t)b * (H_ * W_);

    // thresholds from packed argmax (written by k_search)
    unsigned long long pk = packed[b];
    unsigned am = 0xFFFFFFFFu - (unsigned)(pk & 0xFFFFFFFFull);
    int ti = (int)(am / NT);
    int tj = (int)(am % NT);
    const float t1 = (float)(ti + 1) / 255.0f;
    const float t2 = (float)(tj + 1) / 255.0f;

    if (tid < 128) {
        int r = tid >> 3, cc = tid & 7;
        s_v[r][cc < 4 ? cc : 512 + cc] = 0.0f;
    }
    float4 l[12];
#pragma unroll
    for (int k = 0; k < 12; ++k) {
        int gr = rbase - 2 + k;
        if ((unsigned)gr < (unsigned)H_)
            l[k] = *(const float4*)(lab + (size_t)gr * W_ + c0);
        else
            l[k] = make_float4(0.f, 0.f, 0.f, 0.f);
    }
#pragma unroll
    for (int r = 0; r < 8; ++r) {
        float4 m;
        m.x = max5(l[r].x, l[r+1].x, l[r+2].x, l[r+3].x, l[r+4].x);
        m.y = max5(l[r].y, l[r+1].y, l[r+2].y, l[r+3].y, l[r+4].y);
        m.z = max5(l[r].z, l[r+1].z, l[r+2].z, l[r+3].z, l[r+4].z);
        m.w = max5(l[r].w, l[r+1].w, l[r+2].w, l[r+3].w, l[r+4].w);
        *(float4*)&s_v[half * 8 + r][c0 + 4] = m;
    }
    __syncthreads();

    float acc = 0.0f;
#pragma unroll
    for (int r = 0; r < 8; ++r) {
        const float* f = &s_v[half * 8 + r][c0 + 2];
        float h0 = max5(f[0], f[1], f[2], f[3], f[4]);
        float h1 = max5(f[1], f[2], f[3], f[4], f[5]);
        float h2 = max5(f[2], f[3], f[4], f[5], f[6]);
        float h3 = max5(f[3], f[4], f[5], f[6], f[7]);
        if (h0 > 0.f || h1 > 0.f || h2 > 0.f || h3 > 0.f) {
            size_t off = (size_t)(rbase + r) * W_ + c0;
            float4 iv = *(const float4*)(img + off);
            float4 pv = *(const float4*)(prd + off);
            if (h0 > 0.f) { float ci = iv.x >= t2 ? 1.f : (iv.x >= t1 ? 0.5f : 0.f); float d = ci - pv.x; acc += d * d; }
            if (h1 > 0.f) { float ci = iv.y >= t2 ? 1.f : (iv.y >= t1 ? 0.5f : 0.f); float d = ci - pv.y; acc += d * d; }
            if (h2 > 0.f) { float ci = iv.z >= t2 ? 1.f : (iv.z >= t1 ? 0.5f : 0.f); float d = ci - pv.z; acc += d * d; }
            if (h3 > 0.f) { float ci = iv.w >= t2 ? 1.f : (iv.w >= t1 ? 0.5f : 0.f); float d = ci - pv.w; acc += d * d; }
        }
    }
    s_red[tid] = acc;
    __syncthreads();
    for (int off = 128; off > 0; off >>= 1) {
        if (tid < off) s_red[tid] += s_red[tid + off];
        __syncthreads();
    }
    if (tid == 0) {
        atomicAdd(&sq[b], s_red[0]);
        __threadfence();
        s_ticket = atomicAdd(counter, 1);
    }
    __syncthreads();

    if (s_ticket == B_ * 32 - 1) {   // last block: final valid-batch mean
        if (tid < 64) {
            float lp = 0.0f, vc = 0.0f;
            if (tid < B_) {
                float sqv = atomicAdd(&sq[tid], 0.0f);   // device-scope read
                float smv = sm[tid] + 1e-8f;
                if (smv > 1e-8f) { lp = sqv / smv; vc = 1.0f; }
            }
            for (int off = 32; off > 0; off >>= 1) {
                lp += __shfl_down(lp, off);
                vc += __shfl_down(vc, off);
            }
            if (tid == 0) out[0] = vc > 0.0f ? lp / fmaxf(vc, 1.0f) : 0.0f;
        }
    }
}

extern "C" void kernel_launch(void* const* d_in, const int* in_sizes, int n_in,
                              void* d_out, int out_size, void* d_ws, size_t ws_size,
                              hipStream_t stream) {
    const float* preds  = (const float*)d_in[0];
    const float* labels = (const float*)d_in[1];
    const float* images = (const float*)d_in[2];
    float* out = (float*)d_out;

    char* ws = (char*)d_ws;
    int*                hist    = (int*)ws;                        // 32 KB
    unsigned long long* packed  = (unsigned long long*)(ws + 32768);
    float*              sq      = (float*)(ws + 33024);
    float*              sm      = (float*)(ws + 33152);
    int*                counter = (int*)(ws + 33280);

    hipMemsetAsync(ws, 0, 33296, stream);   // hist + packed + sq + counter

    dim3 gdil(32, B_);   // 32 bands x 32 batches = 1024 blocks (4/CU resident)
    k_hist<<<gdil, 256, 0, stream>>>(labels, images, hist);
    k_search<<<dim3(8, B_), 256, 0, stream>>>(hist, packed, sm);
    k_loss<<<gdil, 256, 0, stream>>>(labels, images, preds, packed, sq, sm,
                                     counter, out);
}